// Round 1
// baseline (166.196 us; speedup 1.0000x reference)
//
#include <hip/hip_runtime.h>
#include <hip/hip_bf16.h>

#define BB 2048
#define AA 96
#define NIN 128
#define NHID 64

typedef __attribute__((ext_vector_type(8))) short bf16x8;
typedef __attribute__((ext_vector_type(4))) float f32x4;

// manual RNE for prep (tiny, once); main kernel uses HW v_cvt_pk
static __device__ __forceinline__ unsigned short f2bf(float x) {
    unsigned u = __builtin_bit_cast(unsigned, x);
    return (unsigned short)((u + 0x7FFFu + ((u >> 16) & 1u)) >> 16);
}
static __device__ __forceinline__ unsigned cvt_pk_hw(float a, float b) {
    __hip_bfloat162 h = __float22bfloat162_rn(make_float2(a, b));
    unsigned u; __builtin_memcpy(&u, &h, 4);   // memcpy: no triviality requirement
    return u;
}

// ws image (16896 B):
//   [0,16384)     bf16 frag image, 1024 frags x 16B, fid = (s*4+t)*64 + lane
//                 lane's elems: k = s*32 + (lane>>4)*8 + j, n = t*16 + (lane&15)
//                 (byte-identical to the R8-validated LDS layout)
//   [16384,16640) b1 f32[64]
//   [16640,16896) w2 f32[64]
// prep also zeroes the output vector: folds the hipMemsetAsync dispatch (3 -> 2).
__global__ void prep_kernel(const float* __restrict__ w1,
                            const float* __restrict__ b1,
                            const float* __restrict__ w2,
                            unsigned char* __restrict__ ws,
                            float* __restrict__ out, int out_n) {
    const int gid = blockIdx.x * 256 + threadIdx.x;
    if (gid < 1024) {
        const int lane = gid & 63, st = gid >> 6;
        const int s = st >> 2, t = st & 3;
        const int k0 = s * 32 + (lane >> 4) * 8;
        const int n  = t * 16 + (lane & 15);
        unsigned short o[8];
        #pragma unroll
        for (int j = 0; j < 8; ++j) o[j] = f2bf(w1[(k0 + j) * NHID + n]);
        uint4 v; __builtin_memcpy(&v, o, 16);
        ((uint4*)ws)[gid] = v;
    } else if (gid < 1088) {
        ((float*)(ws + 16384))[gid - 1024] = b1[gid - 1024];
    } else if (gid < 1152) {
        ((float*)(ws + 16640))[gid - 1088] = w2[gid - 1088];
    } else if (gid - 1152 < out_n) {
        out[gid - 1152] = 0.0f;
    }
}

// wave = one 16-atom x 64-hid tile (mfma_f32_16x16x32_bf16). 3072 blocks.
// R10 change: NO LDS, NO barrier. The 16.6 KB frag image is L1/L2-resident
// (12 blocks/CU re-read it -> hits after first touch), and lane l reading
// frag [s*256 + t*64 + l] is a perfectly coalesced global_load_dwordx4.
// The old __syncthreads forced a vmcnt(0)+lgkmcnt(0) drain of the 8 HBM rep
// loads, block-coupling every wave to a full cold-HBM exposure -- that was
// the serializer (0.62 TB/s at a 16 us streaming floor). Waves are now fully
// independent: one latency exposure each, hidden by 4 independent waves/SIMD.
// Layouts validated R6/R8 (absmax 0.0625): A m=nl,k=quad*8+j; C atom=quad*4+r, hid=nl.
__global__ __launch_bounds__(256, 4) void atomwise_kernel(
    const float* __restrict__ rep,
    const int*   __restrict__ zs,
    const float* __restrict__ mask,
    const unsigned char* __restrict__ ws,   // frag image + b1 + w2
    const float* __restrict__ b2,
    const float* __restrict__ aref,
    const float* __restrict__ mean,
    const float* __restrict__ stddev,
    float* __restrict__ out)
{
    const int tid  = threadIdx.x;
    const int lane = tid & 63;
    const int wv   = tid >> 6;
    const int nl   = lane & 15;
    const int quad = lane >> 4;
    const int atom0 = (blockIdx.x * 4 + wv) * 16;

    // rep loads first (oldest in vm queue; the only HBM traffic)
    const float* rowp = rep + (size_t)(atom0 + nl) * NIN + quad * 8;
    float4 q[8];
    #pragma unroll
    for (int s = 0; s < 4; ++s) {
        q[2 * s]     = *(const float4*)(rowp + s * 32);
        q[2 * s + 1] = *(const float4*)(rowp + s * 32 + 4);
    }

    // epilogue operands prefetched in parallel (no serial lane-0 chain)
    const int   ag    = atom0 + quad * 4 + (nl & 3);
    const float mq    = mask[ag];
    const float arefv = aref[zs[ag]];

    const bf16x8* w1f = (const bf16x8*)ws;
    const float*  b1s = (const float*)(ws + 16384);
    const float*  w2s = (const float*)(ws + 16640);

    // hoist epilogue vectors so the tail has no dependent L1 latency
    float b1v[4], w2v[4];
    #pragma unroll
    for (int t = 0; t < 4; ++t) {
        b1v[t] = b1s[t * 16 + nl];
        w2v[t] = w2s[t * 16 + nl];
    }

    const float sdv  = stddev[0];
    const float cadd = fmaf(b2[0], sdv, mean[0]);
    const float LOG2E = 1.4426950408889634f;
    const float LN2   = 0.6931471805599453f;

    f32x4 acc[4];
    #pragma unroll
    for (int t = 0; t < 4; ++t) acc[t] = (f32x4){0.f, 0.f, 0.f, 0.f};

    #pragma unroll
    for (int s = 0; s < 4; ++s) {
        union { bf16x8 v; unsigned u[4]; } fa;
        fa.u[0] = cvt_pk_hw(q[2 * s].x,     q[2 * s].y);
        fa.u[1] = cvt_pk_hw(q[2 * s].z,     q[2 * s].w);
        fa.u[2] = cvt_pk_hw(q[2 * s + 1].x, q[2 * s + 1].y);
        fa.u[3] = cvt_pk_hw(q[2 * s + 1].z, q[2 * s + 1].w);
        const bf16x8* fr = &w1f[s * 256 + lane];   // coalesced dwordx4, L1-hit
        #pragma unroll
        for (int t = 0; t < 4; ++t)
            acc[t] = __builtin_amdgcn_mfma_f32_16x16x32_bf16(fa.v, fr[t * 64], acc[t], 0, 0, 0);
    }

    // softplus + dot(w2) ; xor-reduce leaves per-quad sums in all 16 lanes
    float v[4];
    #pragma unroll
    for (int r = 0; r < 4; ++r) {
        float p = 0.f;
        #pragma unroll
        for (int t = 0; t < 4; ++t) {
            float x  = acc[t][r] + b1v[t];
            float ax = fabsf(x);
            float em = exp2f(-ax * LOG2E);
            float sp = fmaxf(x, 0.f) + log2f(1.f + em) * LN2;
            p = fmaf(sp - LN2, w2v[t], p);
        }
        p += __shfl_xor(p, 1); p += __shfl_xor(p, 2);
        p += __shfl_xor(p, 4); p += __shfl_xor(p, 8);
        v[r] = p;
    }

    // lanes nl<4 own atom quad*4+nl; select v[nl] without dynamic indexing
    const int rsel = nl & 3;
    float vr = v[0];
    vr = rsel == 1 ? v[1] : vr;
    vr = rsel == 2 ? v[2] : vr;
    vr = rsel == 3 ? v[3] : vr;
    float contrib = (nl < 4) ? mq * (fmaf(vr, sdv, cadd) + arefv) : 0.f;
    #pragma unroll
    for (int off = 32; off; off >>= 1) contrib += __shfl_xor(contrib, off);
    if (lane == 0) atomicAdd(out + atom0 / AA, contrib);   // 16 | 96: one molecule/tile
}

extern "C" void kernel_launch(void* const* d_in, const int* in_sizes, int n_in,
                              void* d_out, int out_size, void* d_ws, size_t ws_size,
                              hipStream_t stream) {
    const float* rep    = (const float*)d_in[0];
    const int*   zs     = (const int*)  d_in[1];
    const float* mask   = (const float*)d_in[2];
    const float* w1     = (const float*)d_in[3];
    const float* b1     = (const float*)d_in[4];
    const float* w2     = (const float*)d_in[5];
    const float* b2     = (const float*)d_in[6];
    const float* aref   = (const float*)d_in[7];
    const float* mean   = (const float*)d_in[8];
    const float* stddev = (const float*)d_in[9];
    float* out = (float*)d_out;
    unsigned char* ws = (unsigned char*)d_ws;

    // prep also zeroes out: 2 dispatches total (was 3 with hipMemsetAsync)
    const int prep_threads = 1152 + out_size;
    const int prep_blocks  = (prep_threads + 255) / 256;
    prep_kernel<<<dim3(prep_blocks), dim3(256), 0, stream>>>(w1, b1, w2, ws, out, out_size);

    const int blocks = (BB * AA) / (4 * 16);     // 3072: wave = one 16-atom tile
    atomwise_kernel<<<dim3(blocks), dim3(256), 0, stream>>>(
        rep, zs, mask, ws, b2, aref, mean, stddev, out);
}

// Round 2
// 163.872 us; speedup vs baseline: 1.0142x; 1.0142x over previous
//
#include <hip/hip_runtime.h>
#include <hip/hip_bf16.h>

#define BB 2048
#define AA 96
#define NIN 128
#define NHID 64

typedef __attribute__((ext_vector_type(8))) short bf16x8;
typedef __attribute__((ext_vector_type(4))) float f32x4;

// manual RNE for prep (tiny, once); main kernel uses HW v_cvt_pk
static __device__ __forceinline__ unsigned short f2bf(float x) {
    unsigned u = __builtin_bit_cast(unsigned, x);
    return (unsigned short)((u + 0x7FFFu + ((u >> 16) & 1u)) >> 16);
}
static __device__ __forceinline__ unsigned cvt_pk_hw(float a, float b) {
    __hip_bfloat162 h = __float22bfloat162_rn(make_float2(a, b));
    unsigned u; __builtin_memcpy(&u, &h, 4);   // memcpy: no triviality requirement
    return u;
}

// ws image (16896 B):
//   [0,16384)     bf16 frag image, 1024 frags x 16B, fid = (s*4+t)*64 + lane
//                 lane's elems: k = s*32 + (lane>>4)*8 + j, n = t*16 + (lane&15)
//                 (byte-identical to the R8-validated LDS layout)
//   [16384,16640) b1 f32[64]
//   [16640,16896) w2 f32[64]
// prep also zeroes the output vector (folds the memset dispatch).
__global__ void prep_kernel(const float* __restrict__ w1,
                            const float* __restrict__ b1,
                            const float* __restrict__ w2,
                            unsigned char* __restrict__ ws,
                            float* __restrict__ out, int out_n) {
    const int gid = blockIdx.x * 256 + threadIdx.x;
    if (gid < 1024) {
        const int lane = gid & 63, st = gid >> 6;
        const int s = st >> 2, t = st & 3;
        const int k0 = s * 32 + (lane >> 4) * 8;
        const int n  = t * 16 + (lane & 15);
        unsigned short o[8];
        #pragma unroll
        for (int j = 0; j < 8; ++j) o[j] = f2bf(w1[(k0 + j) * NHID + n]);
        uint4 v; __builtin_memcpy(&v, o, 16);
        ((uint4*)ws)[gid] = v;
    } else if (gid < 1088) {
        ((float*)(ws + 16384))[gid - 1024] = b1[gid - 1024];
    } else if (gid < 1152) {
        ((float*)(ws + 16640))[gid - 1088] = w2[gid - 1088];
    } else if (gid - 1152 < out_n) {
        out[gid - 1152] = 0.0f;
    }
}

// per-tile epilogue: softplus + dot(w2), xor-reduce within quad; returns the
// per-atom value selected for lanes nl&3. All indexing compile-time (rule #20).
static __device__ __forceinline__ float tile_reduce(const f32x4* acc,
                                                    const float* b1v,
                                                    const float* w2v,
                                                    int nl) {
    const float LOG2E = 1.4426950408889634f;
    const float LN2   = 0.6931471805599453f;
    float v[4];
    #pragma unroll
    for (int r = 0; r < 4; ++r) {
        float p = 0.f;
        #pragma unroll
        for (int t = 0; t < 4; ++t) {
            float x  = acc[t][r] + b1v[t];
            float ax = fabsf(x);
            float em = exp2f(-ax * LOG2E);
            float sp = fmaxf(x, 0.f) + log2f(1.f + em) * LN2;
            p = fmaf(sp - LN2, w2v[t], p);
        }
        p += __shfl_xor(p, 1); p += __shfl_xor(p, 2);
        p += __shfl_xor(p, 4); p += __shfl_xor(p, 8);
        v[r] = p;
    }
    const int rsel = nl & 3;
    float vr = v[0];
    vr = rsel == 1 ? v[1] : vr;
    vr = rsel == 2 ? v[2] : vr;
    vr = rsel == 3 ? v[3] : vr;
    return vr;
}

// R11: wave = TWO 16-atom x 64-hid tiles (32 atoms, one molecule: 32 | 96).
// 1536 blocks x 4 waves. Fixes BOTH prior serializers:
//  - frags staged in LDS (fixed ~120cy latency; immune to L2 eviction by the
//    100MB rep stream, which was refetching the 16.6KB image from L3/HBM
//    mid-MFMA-loop in R10);
//  - rep loads issued AFTER __syncthreads, so the barrier's vmcnt(0) drains
//    only the 17 staging loads once per block -- not per-wave HBM exposures
//    (the R9 serializer).
// Rep loads are nontemporal (zero reuse; keeps L1/L2 for the ws image).
// 2 tiles share frag reads, halve atomics, and double in-flight HBM bytes
// per wave (16 dwordx4) at ~3 waves/SIMD.
// Layouts validated R6/R8 (absmax 0.0625): A m=nl,k=quad*8+j; C atom=quad*4+r, hid=nl.
__global__ __launch_bounds__(256, 3) void atomwise_kernel(
    const float* __restrict__ rep,
    const int*   __restrict__ zs,
    const float* __restrict__ mask,
    const unsigned char* __restrict__ ws,   // frag image + b1 + w2
    const float* __restrict__ b2,
    const float* __restrict__ aref,
    const float* __restrict__ mean,
    const float* __restrict__ stddev,
    float* __restrict__ out)
{
    __shared__ unsigned char smem[16896];

    const int tid  = threadIdx.x;
    const int lane = tid & 63;
    const int wv   = tid >> 6;
    const int nl   = lane & 15;
    const int quad = lane >> 4;
    const int atom0 = (blockIdx.x * 4 + wv) * 32;   // tiles [atom0,+16) and [+16,+32)

    // stage image -> LDS first: linear, coalesced, conflict-free ds_write_b128.
    // The barrier drains ONLY these loads (rep not yet issued).
    {
        const uint4* src = (const uint4*)ws;
        uint4*       dst = (uint4*)smem;
        #pragma unroll
        for (int i = 0; i < 4; ++i) dst[tid + i * 256] = src[tid + i * 256];
        if (tid < 32) dst[1024 + tid] = src[1024 + tid];
    }
    __syncthreads();

    // epilogue operands (small, independent; aref chains off zs)
    const int   ag0   = atom0 + quad * 4 + (nl & 3);
    const int   ag1   = ag0 + 16;
    const float mq0   = mask[ag0];
    const float mq1   = mask[ag1];
    const float aref0 = aref[zs[ag0]];
    const float aref1 = aref[zs[ag1]];

    // ALL rep HBM traffic issued here, post-barrier, nontemporal.
    const float* rowp0 = rep + (size_t)(atom0 + nl) * NIN + quad * 8;
    const float* rowp1 = rowp0 + 16 * NIN;
    f32x4 q0[8], q1[8];
    #pragma unroll
    for (int s = 0; s < 4; ++s) {
        q0[2 * s]     = __builtin_nontemporal_load((const f32x4*)(rowp0 + s * 32));
        q0[2 * s + 1] = __builtin_nontemporal_load((const f32x4*)(rowp0 + s * 32 + 4));
        q1[2 * s]     = __builtin_nontemporal_load((const f32x4*)(rowp1 + s * 32));
        q1[2 * s + 1] = __builtin_nontemporal_load((const f32x4*)(rowp1 + s * 32 + 4));
    }

    const bf16x8* w1f = (const bf16x8*)smem;
    const float*  b1s = (const float*)(smem + 16384);
    const float*  w2s = (const float*)(smem + 16640);

    float b1v[4], w2v[4];
    #pragma unroll
    for (int t = 0; t < 4; ++t) {
        b1v[t] = b1s[t * 16 + nl];
        w2v[t] = w2s[t * 16 + nl];
    }

    const float sdv  = stddev[0];
    const float cadd = fmaf(b2[0], sdv, mean[0]);

    f32x4 acc0[4], acc1[4];
    #pragma unroll
    for (int t = 0; t < 4; ++t) {
        acc0[t] = (f32x4){0.f, 0.f, 0.f, 0.f};
        acc1[t] = (f32x4){0.f, 0.f, 0.f, 0.f};
    }

    #pragma unroll
    for (int s = 0; s < 4; ++s) {
        union { bf16x8 v; unsigned u[4]; } fa0, fa1;
        fa0.u[0] = cvt_pk_hw(q0[2 * s].x,     q0[2 * s].y);
        fa0.u[1] = cvt_pk_hw(q0[2 * s].z,     q0[2 * s].w);
        fa0.u[2] = cvt_pk_hw(q0[2 * s + 1].x, q0[2 * s + 1].y);
        fa0.u[3] = cvt_pk_hw(q0[2 * s + 1].z, q0[2 * s + 1].w);
        fa1.u[0] = cvt_pk_hw(q1[2 * s].x,     q1[2 * s].y);
        fa1.u[1] = cvt_pk_hw(q1[2 * s].z,     q1[2 * s].w);
        fa1.u[2] = cvt_pk_hw(q1[2 * s + 1].x, q1[2 * s + 1].y);
        fa1.u[3] = cvt_pk_hw(q1[2 * s + 1].z, q1[2 * s + 1].w);
        const bf16x8* fr = &w1f[s * 256 + lane];
        #pragma unroll
        for (int t = 0; t < 4; ++t) {
            bf16x8 w = fr[t * 64];   // one LDS read feeds both tiles
            acc0[t] = __builtin_amdgcn_mfma_f32_16x16x32_bf16(fa0.v, w, acc0[t], 0, 0, 0);
            acc1[t] = __builtin_amdgcn_mfma_f32_16x16x32_bf16(fa1.v, w, acc1[t], 0, 0, 0);
        }
    }

    const float vr0 = tile_reduce(acc0, b1v, w2v, nl);
    const float vr1 = tile_reduce(acc1, b1v, w2v, nl);

    float c0 = (nl < 4) ? mq0 * (fmaf(vr0, sdv, cadd) + aref0) : 0.f;
    float c1 = (nl < 4) ? mq1 * (fmaf(vr1, sdv, cadd) + aref1) : 0.f;
    float contrib = c0 + c1;
    #pragma unroll
    for (int off = 32; off; off >>= 1) contrib += __shfl_xor(contrib, off);
    if (lane == 0) atomicAdd(out + atom0 / AA, contrib);   // 32 | 96: one molecule/wave
}

extern "C" void kernel_launch(void* const* d_in, const int* in_sizes, int n_in,
                              void* d_out, int out_size, void* d_ws, size_t ws_size,
                              hipStream_t stream) {
    const float* rep    = (const float*)d_in[0];
    const int*   zs     = (const int*)  d_in[1];
    const float* mask   = (const float*)d_in[2];
    const float* w1     = (const float*)d_in[3];
    const float* b1     = (const float*)d_in[4];
    const float* w2     = (const float*)d_in[5];
    const float* b2     = (const float*)d_in[6];
    const float* aref   = (const float*)d_in[7];
    const float* mean   = (const float*)d_in[8];
    const float* stddev = (const float*)d_in[9];
    float* out = (float*)d_out;
    unsigned char* ws = (unsigned char*)d_ws;

    // prep also zeroes out: 2 dispatches total
    const int prep_threads = 1152 + out_size;
    const int prep_blocks  = (prep_threads + 255) / 256;
    prep_kernel<<<dim3(prep_blocks), dim3(256), 0, stream>>>(w1, b1, w2, ws, out, out_size);

    const int blocks = (BB * AA) / (4 * 32);     // 1536: wave = two 16-atom tiles
    atomwise_kernel<<<dim3(blocks), dim3(256), 0, stream>>>(
        rep, zs, mask, ws, b2, aref, mean, stddev, out);
}